// Round 1
// baseline (275.646 us; speedup 1.0000x reference)
//
#include <hip/hip_runtime.h>
#include <hip/hip_bf16.h>

#define C_IN   256
#define C_OUT  512
#define NFILT  4

#define BM 128
#define BN 128
#define BK 32
#define SAS 40   // LDS row stride in bf16 elems: 80 B, keeps 16B alignment, 2-way max bank alias

typedef __attribute__((ext_vector_type(8))) short bf16x8;
typedef __attribute__((ext_vector_type(4))) float floatx4;

union Pack8 { uint4 u; __hip_bfloat16 h[8]; };

__global__ void zero_cnt_kernel(int* __restrict__ cnt) {
    if (threadIdx.x < NFILT) cnt[threadIdx.x] = 0;
}

__global__ void bucketize_kernel(const float* __restrict__ xyz,
                                 int* __restrict__ idxbuf,
                                 int* __restrict__ cnt, int P) {
    int pid = blockIdx.x * blockDim.x + threadIdx.x;
    if (pid >= P) return;
    float x = xyz[pid * 3 + 0];
    float y = xyz[pid * 3 + 1];
    float z = xyz[pid * 3 + 2];
    // match np: non-fused fp32 sum of squares, then sqrt, then strict <
    float r2 = __fadd_rn(__fadd_rn(__fmul_rn(x, x), __fmul_rn(y, y)), __fmul_rn(z, z));
    float r = sqrtf(r2);
    int filt;
    if (r < 1.0f)        filt = 0;
    else if (r < 1.5f)   filt = 1;
    else if (r < 2.0f)   filt = 2;
    else if (r < 100.0f) filt = 3;
    else                 filt = 0;   // argmax over all-false booleans returns 0

    int lane = threadIdx.x & 63;
    for (int f = 0; f < NFILT; ++f) {
        unsigned long long mask = __ballot(filt == f);
        if (mask == 0ull) continue;
        int leader = __ffsll((unsigned long long)mask) - 1;
        int base = 0;
        if (lane == leader) base = atomicAdd(&cnt[f], __popcll(mask));
        base = __shfl(base, leader);
        if (filt == f) {
            int off = __popcll(mask & ((1ull << lane) - 1ull));
            idxbuf[f * P + base + off] = pid;
        }
    }
}

__global__ void convert_w_kernel(const float* __restrict__ w,
                                 ushort* __restrict__ wb) {
    int i = (blockIdx.x * blockDim.x + threadIdx.x) * 4;
    float4 v = *(const float4*)(w + i);
    union { ushort4 u; __hip_bfloat16 h[4]; } cv;
    cv.h[0] = __float2bfloat16(v.x);
    cv.h[1] = __float2bfloat16(v.y);
    cv.h[2] = __float2bfloat16(v.z);
    cv.h[3] = __float2bfloat16(v.w);
    *(ushort4*)(wb + i) = cv.u;
}

__global__ __launch_bounds__(256) void gemm_kernel(
    const float* __restrict__ feat, const ushort* __restrict__ wb,
    const float* __restrict__ bias, const int* __restrict__ idxbuf,
    const int* __restrict__ cnt, float* __restrict__ out, int P)
{
    __shared__ ushort sA[BM * SAS];
    __shared__ ushort sB[BN * SAS];
    __shared__ int    sIdx[BM];
    __shared__ float  sBias[BN];

    // ---- map linear row-tile (blockIdx.y) onto (bucket f, local tile lt) ----
    int t = blockIdx.y;
    int counts[4];
    counts[0] = cnt[0]; counts[1] = cnt[1]; counts[2] = cnt[2]; counts[3] = cnt[3];
    int f = -1, lt = 0;
    for (int ff = 0; ff < 4; ++ff) {
        int nt = (counts[ff] + BM - 1) / BM;
        if (t < nt) { f = ff; lt = t; break; }
        t -= nt;
    }
    if (f < 0) return;

    int tid = threadIdx.x;
    int oBase = blockIdx.x * BN;
    int rowBase = lt * BM;
    int cn = counts[f];

    if (tid < BM) {
        int r = rowBase + tid;
        sIdx[tid] = (r < cn) ? idxbuf[f * P + r] : -1;
    }
    if (tid < BN) sBias[tid] = bias[f * C_OUT + oBase + tid];
    __syncthreads();

    // ---- staging assignment: thread covers 16 elems of one row per K-step ----
    int sRow = tid >> 1;       // 0..127
    int sHalf = tid & 1;       // 0..1
    int myIdx = sIdx[sRow];
    const float* aRow = feat + (size_t)(myIdx < 0 ? 0 : myIdx) * C_IN + sHalf * 16;
    const ushort* bRow = wb + (size_t)(f * C_OUT + oBase + sRow) * C_IN + sHalf * 16;

    int wid = tid >> 6;
    int lane = tid & 63;
    int wm = (wid >> 1) * 64;
    int wn = (wid & 1) * 64;
    int lcol = lane & 15;
    int quad = lane >> 4;

    floatx4 acc[4][4];
#pragma unroll
    for (int i = 0; i < 4; ++i)
#pragma unroll
        for (int j = 0; j < 4; ++j)
            acc[i][j] = (floatx4){0.f, 0.f, 0.f, 0.f};

    for (int kk = 0; kk < C_IN; kk += BK) {
        // load A slice: 16 fp32
        const float* ap = aRow + kk;
        float4 a0 = *(const float4*)(ap + 0);
        float4 a1 = *(const float4*)(ap + 4);
        float4 a2 = *(const float4*)(ap + 8);
        float4 a3 = *(const float4*)(ap + 12);
        // load B slice: 16 bf16
        const ushort* bp = bRow + kk;
        uint4 b01 = *(const uint4*)(bp + 0);
        uint4 b23 = *(const uint4*)(bp + 8);

        // convert A -> bf16, pack
        Pack8 p0, p1;
        p0.h[0] = __float2bfloat16(a0.x); p0.h[1] = __float2bfloat16(a0.y);
        p0.h[2] = __float2bfloat16(a0.z); p0.h[3] = __float2bfloat16(a0.w);
        p0.h[4] = __float2bfloat16(a1.x); p0.h[5] = __float2bfloat16(a1.y);
        p0.h[6] = __float2bfloat16(a1.z); p0.h[7] = __float2bfloat16(a1.w);
        p1.h[0] = __float2bfloat16(a2.x); p1.h[1] = __float2bfloat16(a2.y);
        p1.h[2] = __float2bfloat16(a2.z); p1.h[3] = __float2bfloat16(a2.w);
        p1.h[4] = __float2bfloat16(a3.x); p1.h[5] = __float2bfloat16(a3.y);
        p1.h[6] = __float2bfloat16(a3.z); p1.h[7] = __float2bfloat16(a3.w);

        ushort* dA = &sA[sRow * SAS + sHalf * 16];
        *(uint4*)(dA + 0) = p0.u;
        *(uint4*)(dA + 8) = p1.u;
        ushort* dB = &sB[sRow * SAS + sHalf * 16];
        *(uint4*)(dB + 0) = b01;
        *(uint4*)(dB + 8) = b23;

        __syncthreads();

        bf16x8 af[4], bfr[4];
#pragma unroll
        for (int i = 0; i < 4; ++i)
            af[i] = *(const bf16x8*)&sA[(wm + i * 16 + lcol) * SAS + quad * 8];
#pragma unroll
        for (int j = 0; j < 4; ++j)
            bfr[j] = *(const bf16x8*)&sB[(wn + j * 16 + lcol) * SAS + quad * 8];
#pragma unroll
        for (int i = 0; i < 4; ++i)
#pragma unroll
            for (int j = 0; j < 4; ++j)
                acc[i][j] = __builtin_amdgcn_mfma_f32_16x16x32_bf16(af[i], bfr[j], acc[i][j], 0, 0, 0);

        __syncthreads();
    }

    // ---- epilogue: scatter rows by original point id, add bias ----
#pragma unroll
    for (int i = 0; i < 4; ++i) {
        int r0 = wm + i * 16 + quad * 4;
        int pid0 = sIdx[r0 + 0];
        int pid1 = sIdx[r0 + 1];
        int pid2 = sIdx[r0 + 2];
        int pid3 = sIdx[r0 + 3];
#pragma unroll
        for (int j = 0; j < 4; ++j) {
            int o = oBase + wn + j * 16 + lcol;
            float bv = sBias[wn + j * 16 + lcol];
            if (pid0 >= 0) out[pid0 * C_OUT + o] = acc[i][j][0] + bv;
            if (pid1 >= 0) out[pid1 * C_OUT + o] = acc[i][j][1] + bv;
            if (pid2 >= 0) out[pid2 * C_OUT + o] = acc[i][j][2] + bv;
            if (pid3 >= 0) out[pid3 * C_OUT + o] = acc[i][j][3] + bv;
        }
    }
}

extern "C" void kernel_launch(void* const* d_in, const int* in_sizes, int n_in,
                              void* d_out, int out_size, void* d_ws, size_t ws_size,
                              hipStream_t stream) {
    const float* feat = (const float*)d_in[0];
    const float* xyz  = (const float*)d_in[1];
    const float* w    = (const float*)d_in[2];
    const float* bias = (const float*)d_in[3];
    float* out = (float*)d_out;
    int P = in_sizes[0] / C_IN;

    char* ws = (char*)d_ws;
    int* idxbuf = (int*)ws;                                    // 4*P ints
    int* cntp   = (int*)(ws + (size_t)4 * P * 4);              // 4 ints
    ushort* wb  = (ushort*)(ws + (size_t)4 * P * 4 + 16);      // NFILT*C_OUT*C_IN bf16

    zero_cnt_kernel<<<1, 64, 0, stream>>>(cntp);
    bucketize_kernel<<<(P + 255) / 256, 256, 0, stream>>>(xyz, idxbuf, cntp, P);
    convert_w_kernel<<<(NFILT * C_OUT * C_IN) / 1024, 256, 0, stream>>>(w, wb);

    dim3 grid(C_OUT / BN, P / BM + NFILT);
    gemm_kernel<<<grid, 256, 0, stream>>>(feat, wb, bias, idxbuf, cntp, out, P);
}